// Round 9
// baseline (226.020 us; speedup 1.0000x reference)
//
#include <hip/hip_runtime.h>
#include <hip/hip_fp16.h>

#define B_ROWS 2048
#define C_COLS 65536
#define D_DIM  256
#define N_NEG  50
#define NTILES (C_COLS / 128)   // 512 column tiles

typedef __attribute__((ext_vector_type(8))) short short8;
typedef __attribute__((ext_vector_type(16))) float floatx16;

__device__ __forceinline__ uint f2bf(float f) {
  unsigned u = __float_as_uint(f);
  return (u + 0x7FFFu + ((u >> 16) & 1u)) >> 16;  // RNE
}

// ---------------- fp32 -> bf16 convert into 32x32x16 FRAGMENT-MAJOR layouts ----------------
// One thread per 16-B chunk (8 bf16 = one MFMA lane-fragment; lane covers row=lane&31, k=8*(lane>>5)+j).
// fF  chunk idx: [slab(16)][h2(2)][jb(4)][kcl(8)][lane(64)]   (65536 chunks, 1 MB)
//    row = slab*128 + jb*32 + (lane&31); k = h2*128 + kcl*16 + (lane>>5)*8
// cbF chunk idx: [t(512)][ib(4)][kc(16)][lane(64)]            (2097152 chunks, 32 MB)
//    row = t*128 + ib*32 + (lane&31); k = kc*16 + (lane>>5)*8
__global__ void cvt_frag(const float* __restrict__ f, const float* __restrict__ cen,
                         ushort* __restrict__ fF, ushort* __restrict__ cbF) {
  int c = blockIdx.x * blockDim.x + threadIdx.x;
  const float* src; ushort* dst; int row, k;
  if (c < 65536) {
    int ln = c & 63, kcl = (c >> 6) & 7, jb = (c >> 9) & 3, h2 = (c >> 11) & 1, slab = c >> 12;
    row = slab * 128 + jb * 32 + (ln & 31);
    k = h2 * 128 + kcl * 16 + (ln >> 5) * 8;
    src = f; dst = fF + (size_t)c * 8;
  } else {
    int c2 = c - 65536;
    int ln = c2 & 63, kc = (c2 >> 6) & 15, ib = (c2 >> 10) & 3, t = c2 >> 12;
    row = t * 128 + ib * 32 + (ln & 31);
    k = kc * 16 + (ln >> 5) * 8;
    src = cen; dst = cbF + (size_t)c2 * 8;
  }
  const float4* s = (const float4*)(src + (size_t)row * D_DIM + k);
  float4 a = s[0], b = s[1];
  uint4 o;
  o.x = f2bf(a.x) | (f2bf(a.y) << 16);
  o.y = f2bf(a.z) | (f2bf(a.w) << 16);
  o.z = f2bf(b.x) | (f2bf(b.y) << 16);
  o.w = f2bf(b.z) | (f2bf(b.w) << 16);
  *(uint4*)dst = o;
}

__device__ __forceinline__ void async16(const void* g, void* l) {
  __builtin_amdgcn_global_load_lds((const __attribute__((address_space(1))) void*)g,
                                   (__attribute__((address_space(3))) void*)l,
                                   16, 0, 0);
}

// ---------------- fragment GEMM (32x32x16, D[n][m], 2x2/wave) + register 64:1 max ----------------
// 1-D grid 8192, XCD-partitioned: xcd=bid&7 owns tiles [xcd*64, +64); within an XCD the 16 slabs
// of one tile run consecutively (cb tile L2-hot, fetched from HBM once chip-wide).
__global__ __launch_bounds__(256, 4)
void gemm_frag(const ushort* __restrict__ fF, const ushort* __restrict__ cbF,
               const int* __restrict__ label, float* __restrict__ cand) {
  __shared__ __align__(16) ushort Fs[16384];   // 32 KB: f fragments for one 128-K half
  const int tid = threadIdx.x, wave = tid >> 6, lane = tid & 63;
  const int ml = lane & 31, h = lane >> 5;
  const int d = blockIdx.x;
  const int xcd = d & 7, s = d >> 3;
  const int slab = s & 15, t = (s >> 4) + xcd * 64;
  const int m0 = slab * 128, n0 = t * 128;
  const int wn2 = wave >> 1, wm2 = wave & 1;    // 64-wide n/m halves of the 128-tile

  floatx16 acc[2][2] = {};                      // [i: n 32-block][j: m 32-block]
  // cb chunk ((t*4 + wn2*2 + i)*16 + kc): i stride 8192 halves, kc stride 512 halves
  const ushort* aB = cbF + (size_t)(t * 4 + wn2 * 2) * 8192 + lane * 8;

  short8 aC0, aC1, bC0, bC1;
#pragma unroll
  for (int h2 = 0; h2 < 2; ++h2) {
    if (h2) __syncthreads();                    // all waves done with Fs half 0
    const ushort* src = fF + (size_t)(slab * 2 + h2) * 16384;
#pragma unroll
    for (int r = 0; r < 8; ++r)
      async16(src + r * 2048 + wave * 512 + lane * 8, Fs + r * 2048 + wave * 512);
    __syncthreads();                            // staging complete (vmcnt drained)

    {
      const int kc = h2 * 8;
      aC0 = *(const short8*)(aB + kc * 512);
      aC1 = *(const short8*)(aB + 8192 + kc * 512);
      bC0 = *(const short8*)(Fs + (((wm2 * 2 + 0) * 8 + 0) * 64 + lane) * 8);
      bC1 = *(const short8*)(Fs + (((wm2 * 2 + 1) * 8 + 0) * 64 + lane) * 8);
    }
#pragma unroll
    for (int kcl = 0; kcl < 8; ++kcl) {
      short8 aN0, aN1, bN0, bN1;
      if (kcl < 7) {                            // issue next chunk's loads BEFORE this chunk's MFMAs
        const int kc = h2 * 8 + kcl + 1;
        aN0 = *(const short8*)(aB + kc * 512);
        aN1 = *(const short8*)(aB + 8192 + kc * 512);
        bN0 = *(const short8*)(Fs + (((wm2 * 2 + 0) * 8 + kcl + 1) * 64 + lane) * 8);
        bN1 = *(const short8*)(Fs + (((wm2 * 2 + 1) * 8 + kcl + 1) * 64 + lane) * 8);
      }
      acc[0][0] = __builtin_amdgcn_mfma_f32_32x32x16_bf16(aC0, bC0, acc[0][0], 0, 0, 0);
      acc[0][1] = __builtin_amdgcn_mfma_f32_32x32x16_bf16(aC0, bC1, acc[0][1], 0, 0, 0);
      acc[1][0] = __builtin_amdgcn_mfma_f32_32x32x16_bf16(aC1, bC0, acc[1][0], 0, 0, 0);
      acc[1][1] = __builtin_amdgcn_mfma_f32_32x32x16_bf16(aC1, bC1, acc[1][1], 0, 0, 0);
      aC0 = aN0; aC1 = aN1; bC0 = bN0; bC1 = bN1;
    }
  }

  // ---- register epilogue ----
  // D[n][m]: lane holds m = wm2*64 + j*32 + ml; n = wn2*64 + i*32 + (reg&3) + 8*(reg>>2) + 4*h.
  float gm[2];
#pragma unroll
  for (int j = 0; j < 2; ++j) {
    const int lab = label[m0 + wm2 * 64 + j * 32 + ml];
    float v = -INFINITY;
#pragma unroll
    for (int i = 0; i < 2; ++i) {
      const int rel = lab - (n0 + wn2 * 64 + i * 32);
      if ((unsigned)rel < 32u && (((rel >> 2) & 1) == h)) {   // rare: ~0.25 lanes/block
        const int r4 = rel & ~4;
        const int reg = (r4 & 3) | ((r4 >> 3) << 2);
#pragma unroll
        for (int r = 0; r < 16; ++r)
          if (r == reg) acc[i][j][r] = -INFINITY;
      }
#pragma unroll
      for (int r = 0; r < 16; ++r) v = fmaxf(v, acc[i][j][r]);
    }
    v = fmaxf(v, __shfl_xor(v, 32));            // merge h-halves: full 64-n group max
    gm[j] = v;
  }
  const float outv = h ? gm[1] : gm[0];
  const int m = m0 + wm2 * 64 + h * 32 + ml;
  cand[(size_t)m * (NTILES * 2) + t * 2 + wn2] = outv;
}

// fp16-bit monotone key <-> value
__device__ __forceinline__ float dec_key(int k) {
  if (k < 0x0400) return -INFINITY;
  ushort h = (k >= 0x8000) ? (ushort)(k ^ 0x8000) : (ushort)(~k & 0xFFFF);
  __half_raw hr; hr.x = h;
  return __half2float((__half)hr);
}

// ---------------- per-row: top-50 of 1024 pool values + loss, fused mean via atomicAdd ----
__global__ void final_select(const float* __restrict__ cand, const float* __restrict__ f,
                             const float* __restrict__ cen, const int* __restrict__ label,
                             float* __restrict__ out) {
  __shared__ float sred[8];
  __shared__ int   sint[8];
  const int row = blockIdx.x, tid = threadIdx.x;
  const int lane = tid & 63, wid = tid >> 6;
  const int lab = label[row];

  float4 u = ((const float4*)(cand + (size_t)row * (NTILES * 2)))[tid];  // 1024 pool
  float v[4] = {u.x, u.y, u.z, u.w};
  float pv = f[(size_t)row * D_DIM + tid] * cen[(size_t)lab * D_DIM + tid];
  float m = fmaxf(fmaxf(v[0], v[1]), fmaxf(v[2], v[3]));
#pragma unroll
  for (int o = 32; o > 0; o >>= 1) {
    m = fmaxf(m, __shfl_down(m, o));
    pv += __shfl_down(pv, o);
  }
  if (lane == 0) { sred[wid] = m; sred[4 + wid] = pv; }
  __syncthreads();
  m = fmaxf(fmaxf(sred[0], sred[1]), fmaxf(sred[2], sred[3]));
  const float pos = sred[4] + sred[5] + sred[6] + sred[7];

  // bisection seeded at the row-max fp16 key
  __half hm = __float2half(m);
  int hb = (int)(*(ushort*)&hm);
  int km = (m >= 0.f) ? (0x8000 | hb) : (~hb & 0xFFFF);
  int lo = km - 2048, hi = km;
  if (lo < 0x0400) lo = 0x0400;
#pragma unroll
  for (int it = 0; it < 12; ++it) {
    int mid = (lo + hi) >> 1;
    float tau = dec_key(mid);
    int c = (v[0] > tau) + (v[1] > tau) + (v[2] > tau) + (v[3] > tau);
#pragma unroll
    for (int o = 32; o > 0; o >>= 1) c += __shfl_down(c, o);
    if (lane == 0) sint[(it & 1) * 4 + wid] = c;
    __syncthreads();
    int base = (it & 1) * 4;
    int tot = sint[base] + sint[base + 1] + sint[base + 2] + sint[base + 3];
    if (tot <= 49) hi = mid; else lo = mid + 1;
  }

  const float tau = dec_key(hi);
  float sum = 0.f, se = 0.f; int c = 0;
#pragma unroll
  for (int k = 0; k < 4; ++k) {
    if (v[k] > tau) { ++c; sum += v[k]; se += expf(v[k] - m); }
  }
#pragma unroll
  for (int o = 32; o > 0; o >>= 1) {
    sum += __shfl_down(sum, o);
    se  += __shfl_down(se, o);
    c   += __shfl_down(c, o);
  }
  if (lane == 0) { sred[wid] = sum; sred[4 + wid] = se; sint[wid] = c; }
  __syncthreads();
  if (tid == 0) {
    float S = sred[0] + sred[1] + sred[2] + sred[3];
    float E = sred[4] + sred[5] + sred[6] + sred[7];
    int   C = sint[0] + sint[1] + sint[2] + sint[3];
    float nfill = (float)(N_NEG - C);          // ties at tau fill the remainder
    S += nfill * tau;
    E += nfill * expf(tau - m);
    float M = fmaxf(m, pos);
    float seAll = E * expf(m - M) + expf(pos - M);
    float lse = M + logf(seAll);
    // targets [0.9002, 0.0002 x50]: loss = 0.9102*lse - 0.9002*pos - 2e-4*sum(neg)
    float loss = 0.9102f * lse - 0.9002f * pos - 2.0e-4f * S;
    atomicAdd(out, loss * (1.0f / B_ROWS));
  }
}

extern "C" void kernel_launch(void* const* d_in, const int* in_sizes, int n_in,
                              void* d_out, int out_size, void* d_ws, size_t ws_size,
                              hipStream_t stream) {
  const float* f   = (const float*)d_in[0];
  const float* cen = (const float*)d_in[1];
  const int*   label = (const int*)d_in[2];
  float* out = (float*)d_out;

  char* ws = (char*)d_ws;
  float*  cand = (float*)ws;                     // 8 MiB: [2048][1024]
  ushort* fF   = (ushort*)(ws + 8388608);        // 1 MiB fragment-major f
  ushort* cbF  = (ushort*)(ws + 9437184);        // 32 MiB fragment-major centers

  hipMemsetAsync(d_out, 0, out_size * sizeof(float), stream);

  cvt_frag<<<(65536 + 2097152) / 256, 256, 0, stream>>>(f, cen, fF, cbF);

  gemm_frag<<<8192, 256, 0, stream>>>(fF, cbF, label, cand);

  final_select<<<B_ROWS, 256, 0, stream>>>(cand, f, cen, label, out);
}

// Round 10
// 206.478 us; speedup vs baseline: 1.0946x; 1.0946x over previous
//
#include <hip/hip_runtime.h>
#include <hip/hip_fp16.h>

#define B_ROWS 2048
#define C_COLS 65536
#define D_DIM  256
#define N_NEG  50
#define NTILES (C_COLS / 128)   // 512 column tiles

typedef __attribute__((ext_vector_type(8))) short short8;
typedef __attribute__((ext_vector_type(4))) float floatx4;

__device__ __forceinline__ uint f2bf(float f) {
  unsigned u = __float_as_uint(f);
  return (u + 0x7FFFu + ((u >> 16) & 1u)) >> 16;  // RNE
}

// ---------------- fp32 -> bf16 convert into 16x16x32 FRAGMENT-MAJOR regions ----------------
// Region = one (slab|tile, kt) staging block of 8192 halves (16 KB), linear chunk order:
//   cidx = ((rb*2 + ks)*4 + q)*16 + l   (rb = row-block of 16, ks = k-sub32, q = k-quad, l = row&15)
// source: row = base + rb*16 + l ; k = kt*64 + ks*32 + q*8 (8 consecutive elements).
// Thread c: COALESCED 32-B read at (row = c>>5, k = (c&31)*8), scattered 16-B write.
__global__ void cvt_frag(const float* __restrict__ f, const float* __restrict__ cen,
                         ushort* __restrict__ fF, ushort* __restrict__ cbF) {
  int c = blockIdx.x * blockDim.x + threadIdx.x;
  int row = c >> 5, ka = c & 31;
  int kt = ka >> 3, ks = (ka >> 2) & 1, q = ka & 3;
  const float* src; ushort* dstBase; int r;
  if (row < B_ROWS) { src = f; dstBase = fF; r = row; }
  else { src = cen; dstBase = cbF; r = row - B_ROWS; }
  int big = r >> 7, rb = (r >> 4) & 7, l = r & 15;
  const float4* s = (const float4*)(src + (size_t)r * D_DIM + ka * 8);
  float4 a = s[0], b = s[1];
  uint4 o;
  o.x = f2bf(a.x) | (f2bf(a.y) << 16);
  o.y = f2bf(a.z) | (f2bf(a.w) << 16);
  o.z = f2bf(b.x) | (f2bf(b.y) << 16);
  o.w = f2bf(b.z) | (f2bf(b.w) << 16);
  size_t chunk = (size_t)(big * 4 + kt) * 1024 + ((rb * 2 + ks) * 4 + q) * 16 + l;
  *(uint4*)(dstBase + chunk * 8) = o;
}

__device__ __forceinline__ void async16(const void* g, void* l) {
  __builtin_amdgcn_global_load_lds((const __attribute__((address_space(1))) void*)g,
                                   (__attribute__((address_space(3))) void*)l,
                                   16, 0, 0);
}

// ---------------- fragment GEMM (16x16x32, D[n][m], 4x4/wave) + register 64:1 max ----------------
// Both operands staged via global_load_lds from fragment-major regions (linear copy).
// 1-D grid 8192, XCD-partitioned: xcd=d&7 owns tiles [xcd*64,+64); 16 slabs of a tile run
// back-to-back on one XCD (cb region L2-hot, HBM-fetched once chip-wide).
__global__ __launch_bounds__(256, 4)
void gemm_frag(const ushort* __restrict__ fF, const ushort* __restrict__ cbF,
               const int* __restrict__ label, float* __restrict__ cand) {
  __shared__ __align__(16) ushort Cs[8192];    // centers fragments, one BK=64 region
  __shared__ __align__(16) ushort Fs[8192];    // f fragments
  const int tid = threadIdx.x, wave = tid >> 6, lane = tid & 63;
  const int l = lane & 15, q = lane >> 4;
  const int d = blockIdx.x;
  const int xcd = d & 7, s = d >> 3;
  const int slab = s & 15, t = (s >> 4) + xcd * 64;
  const int m0 = slab * 128, n0 = t * 128;
  const int wn = (wave >> 1) * 64, wm = (wave & 1) * 64;

  floatx4 acc[4][4] = {};                      // [i: n-block][j: m-block]

  for (int kt = 0; kt < 4; ++kt) {
    const ushort* aS = cbF + (size_t)(t * 4 + kt) * 8192;
    const ushort* bS = fF  + (size_t)(slab * 4 + kt) * 8192;
#pragma unroll
    for (int r = 0; r < 4; ++r) {
      async16(aS + r * 2048 + wave * 512 + lane * 8, Cs + r * 2048 + wave * 512);
      async16(bS + r * 2048 + wave * 512 + lane * 8, Fs + r * 2048 + wave * 512);
    }
    __syncthreads();                           // vmcnt drained: deposits visible

#pragma unroll
    for (int ks = 0; ks < 2; ++ks) {
      short8 a[4], b[4];
#pragma unroll
      for (int i = 0; i < 4; ++i) {
        a[i] = *(const short8*)(Cs + ((((((wn >> 4) + i) * 2 + ks) * 4 + q) * 16 + l) << 3));
        b[i] = *(const short8*)(Fs + ((((((wm >> 4) + i) * 2 + ks) * 4 + q) * 16 + l) << 3));
      }
#pragma unroll
      for (int i = 0; i < 4; ++i)
#pragma unroll
        for (int j = 0; j < 4; ++j)
          acc[i][j] = __builtin_amdgcn_mfma_f32_16x16x32_bf16(a[i], b[j], acc[i][j], 0, 0, 0);
    }
    if (kt < 3) __syncthreads();               // all reads done before next staging overwrite
  }

  // ---- register epilogue ----
  // D[n][m]: lane holds m = wm + j*16 + l for every reg; n = wn + i*16 + q*4 + reg.
  float gm[4];
#pragma unroll
  for (int j = 0; j < 4; ++j) {
    const int lab = label[m0 + wm + j * 16 + l];
    const int rel = lab - (n0 + wn);
    if ((unsigned)rel < 64u && ((rel >> 2) & 3) == q) {   // rare: ~0.25 lanes/block
      const int ii = rel >> 4, rr = rel & 3;
#pragma unroll
      for (int i = 0; i < 4; ++i)
#pragma unroll
        for (int r = 0; r < 4; ++r)
          if (i == ii && r == rr) acc[i][j][r] = -INFINITY;
    }
    float v = -INFINITY;
#pragma unroll
    for (int i = 0; i < 4; ++i)
      v = fmaxf(v, fmaxf(fmaxf(acc[i][j][0], acc[i][j][1]), fmaxf(acc[i][j][2], acc[i][j][3])));
    v = fmaxf(v, __shfl_xor(v, 16));           // combine q-lanes: full 64-n group max
    v = fmaxf(v, __shfl_xor(v, 32));
    gm[j] = v;
  }
  // lane (q,l) stores gm[q] for m = wm + q*16 + l = wm + lane
  const float outv = (q == 0) ? gm[0] : (q == 1) ? gm[1] : (q == 2) ? gm[2] : gm[3];
  cand[(size_t)(m0 + wm + lane) * (NTILES * 2) + t * 2 + (wn >> 6)] = outv;
}

// fp16-bit monotone key <-> value
__device__ __forceinline__ float dec_key(int k) {
  if (k < 0x0400) return -INFINITY;
  ushort h = (k >= 0x8000) ? (ushort)(k ^ 0x8000) : (ushort)(~k & 0xFFFF);
  __half_raw hr; hr.x = h;
  return __half2float((__half)hr);
}

// ---------------- per-row: top-50 of 1024 pool values + loss, fused mean via atomicAdd ----
__global__ void final_select(const float* __restrict__ cand, const float* __restrict__ f,
                             const float* __restrict__ cen, const int* __restrict__ label,
                             float* __restrict__ out) {
  __shared__ float sred[8];
  __shared__ int   sint[8];
  const int row = blockIdx.x, tid = threadIdx.x;
  const int lane = tid & 63, wid = tid >> 6;
  const int lab = label[row];

  float4 u = ((const float4*)(cand + (size_t)row * (NTILES * 2)))[tid];  // 1024 pool
  float v[4] = {u.x, u.y, u.z, u.w};
  float pv = f[(size_t)row * D_DIM + tid] * cen[(size_t)lab * D_DIM + tid];
  float m = fmaxf(fmaxf(v[0], v[1]), fmaxf(v[2], v[3]));
#pragma unroll
  for (int o = 32; o > 0; o >>= 1) {
    m = fmaxf(m, __shfl_down(m, o));
    pv += __shfl_down(pv, o);
  }
  if (lane == 0) { sred[wid] = m; sred[4 + wid] = pv; }
  __syncthreads();
  m = fmaxf(fmaxf(sred[0], sred[1]), fmaxf(sred[2], sred[3]));
  const float pos = sred[4] + sred[5] + sred[6] + sred[7];

  // bisection seeded at the row-max fp16 key
  __half hm = __float2half(m);
  int hb = (int)(*(ushort*)&hm);
  int km = (m >= 0.f) ? (0x8000 | hb) : (~hb & 0xFFFF);
  int lo = km - 2048, hi = km;
  if (lo < 0x0400) lo = 0x0400;
#pragma unroll
  for (int it = 0; it < 12; ++it) {
    int mid = (lo + hi) >> 1;
    float tau = dec_key(mid);
    int c = (v[0] > tau) + (v[1] > tau) + (v[2] > tau) + (v[3] > tau);
#pragma unroll
    for (int o = 32; o > 0; o >>= 1) c += __shfl_down(c, o);
    if (lane == 0) sint[(it & 1) * 4 + wid] = c;
    __syncthreads();
    int base = (it & 1) * 4;
    int tot = sint[base] + sint[base + 1] + sint[base + 2] + sint[base + 3];
    if (tot <= 49) hi = mid; else lo = mid + 1;
  }

  const float tau = dec_key(hi);
  float sum = 0.f, se = 0.f; int c = 0;
#pragma unroll
  for (int k = 0; k < 4; ++k) {
    if (v[k] > tau) { ++c; sum += v[k]; se += expf(v[k] - m); }
  }
#pragma unroll
  for (int o = 32; o > 0; o >>= 1) {
    sum += __shfl_down(sum, o);
    se  += __shfl_down(se, o);
    c   += __shfl_down(c, o);
  }
  if (lane == 0) { sred[wid] = sum; sred[4 + wid] = se; sint[wid] = c; }
  __syncthreads();
  if (tid == 0) {
    float S = sred[0] + sred[1] + sred[2] + sred[3];
    float E = sred[4] + sred[5] + sred[6] + sred[7];
    int   C = sint[0] + sint[1] + sint[2] + sint[3];
    float nfill = (float)(N_NEG - C);          // ties at tau fill the remainder
    S += nfill * tau;
    E += nfill * expf(tau - m);
    float M = fmaxf(m, pos);
    float seAll = E * expf(m - M) + expf(pos - M);
    float lse = M + logf(seAll);
    // targets [0.9002, 0.0002 x50]: loss = 0.9102*lse - 0.9002*pos - 2e-4*sum(neg)
    float loss = 0.9102f * lse - 0.9002f * pos - 2.0e-4f * S;
    atomicAdd(out, loss * (1.0f / B_ROWS));
  }
}

extern "C" void kernel_launch(void* const* d_in, const int* in_sizes, int n_in,
                              void* d_out, int out_size, void* d_ws, size_t ws_size,
                              hipStream_t stream) {
  const float* f   = (const float*)d_in[0];
  const float* cen = (const float*)d_in[1];
  const int*   label = (const int*)d_in[2];
  float* out = (float*)d_out;

  char* ws = (char*)d_ws;
  float*  cand = (float*)ws;                     // 8 MiB: [2048][1024]
  ushort* fF   = (ushort*)(ws + 8388608);        // 1 MiB fragment-major f
  ushort* cbF  = (ushort*)(ws + 9437184);        // 32 MiB fragment-major centers

  hipMemsetAsync(d_out, 0, out_size * sizeof(float), stream);

  cvt_frag<<<(B_ROWS + C_COLS) * 32 / 256, 256, 0, stream>>>(f, cen, fF, cbF);

  gemm_frag<<<8192, 256, 0, stream>>>(fF, cbF, label, cand);

  final_select<<<B_ROWS, 256, 0, stream>>>(cand, f, cen, label, out);
}